// Round 11
// baseline (256.150 us; speedup 1.0000x reference)
//
#include <hip/hip_runtime.h>

typedef __attribute__((ext_vector_type(8))) short bf16x8;
typedef __attribute__((ext_vector_type(4))) float floatx4;

#define T_TREES 20
#define N_NODES 32      // padded (31 real internal nodes)
#define F_DIM 128
#define M_TILE 128      // 8 waves x 16 rows each, wave-private leaf phase
#define THREADS 512
#define S_SP2 17        // sp stride (dwords): 16 rows + 1 pad, odd -> conflict-free

#define NLOG2E 1.4426950408889634f   // sigmoid scale, applied in EPILOGUE (fma)

__device__ __forceinline__ short f2bf(float f) {
    unsigned u = __float_as_uint(f);
    u += 0x7fffu + ((u >> 16) & 1u);   // RNE — matches numpy/ml_dtypes bf16 cast
    return (short)(u >> 16);
}
__device__ __forceinline__ float bf2f(short h) {
    return __uint_as_float(((unsigned)(unsigned short)h) << 16);
}

// sigma(z) with u = -z*log2(e) already: 1/(1+2^u). 2 VALU + 2 trans ops.
__device__ __forceinline__ float sig_from_scaled(float u) {
    return __builtin_amdgcn_rcpf(1.f + __builtin_amdgcn_exp2f(u));
}

// ---------------- prep: RAW bf16 masked weights (unscaled -> exact bf16 grid).
// Parallel: grid (20 trees, 8 node-slices); tw staged via LDS; softmax order identical.
__global__ void nrf_prep(const float* __restrict__ sw, const float* __restrict__ sb,
                         const float* __restrict__ ll, const float* __restrict__ tw,
                         const float* __restrict__ fm,
                         short* __restrict__ w_all, float* __restrict__ bias_p,
                         float* __restrict__ lv0) {
    int t = blockIdx.x, slice = blockIdx.y, tid = threadIdx.x;

    const float* fmt = fm + t * F_DIM;
    const float* swt = sw + t * 31 * F_DIM;
    int idx = slice * 512 + tid;          // 4 nodes x 128 feats per slice
    #pragma unroll
    for (int r = 0; r < 2; ++r, idx += 256) {
        int n = idx >> 7, f = idx & 127;
        // mask is 0/1: bf16(sw*fm) == bf16(sw)*fm exactly. Store UNSCALED bf16.
        short wb = (n < 31 && fmt[f] != 0.f) ? f2bf(swt[n * F_DIM + f]) : (short)0;
        w_all[t * (N_NODES * F_DIM) + idx] = wb;
    }

    if (slice == 0) {
        __shared__ float tws[T_TREES];
        if (tid < T_TREES) tws[tid] = tw[tid];
        __syncthreads();
        if (tid < N_NODES) {
            // same reduction ORDER as the verified kernel -> bit-identical wt
            float m = -1e30f;
            for (int i = 0; i < T_TREES; ++i) m = fmaxf(m, bf2f(f2bf(tws[i])));
            float s = 0.f;
            for (int i = 0; i < T_TREES; ++i) s += __expf(bf2f(f2bf(tws[i])) - m);
            float wt = __expf(bf2f(f2bf(tws[t])) - m) / s;

            float bv = (tid < 31) ? bf2f(f2bf(sb[t * 31 + tid])) : 0.f;
            bias_p[t * N_NODES + tid] = bv * (-NLOG2E);
            float a  = bf2f(f2bf(ll[(t * 32 + tid) * 2 + 0]));
            float bb = bf2f(f2bf(ll[(t * 32 + tid) * 2 + 1]));
            float mx = fmaxf(a, bb);
            float e0 = __expf(a - mx), e1 = __expf(bb - mx);
            lv0[t * N_NODES + tid] = wt * e0 / (e0 + e1);
        }
    }
}

// ---------------- main: 8 waves x 16 rows (was 4 x 32). Halves per-wave registers
// (afrag 16, acc 8, g 9) so launch_bounds(512,8) fits the 64-reg bin -> 32 waves/CU
// (2x TLP to fill the dependency-chain stalls measured at VALUBusy 40%).
// Per-row op sequence, MFMA chain order, sigmoid, leaf chain: bit-identical to r8.
__global__ __launch_bounds__(THREADS, 8) void nrf_main(const float* __restrict__ x,
        const short* __restrict__ w_all, const float* __restrict__ bias_p,
        const float* __restrict__ lv0, float* __restrict__ out) {
    __shared__ short bstage[2][N_NODES * F_DIM];   // 2 x 8 KB, XOR-swizzled rows
    __shared__ float sp_all[8][N_NODES * S_SP2];   // one 16-row patch per wave
    __shared__ float lv_s[T_TREES * N_NODES];
    __shared__ float bias_s[T_TREES * N_NODES];

    int tid = threadIdx.x;
    int wave = tid >> 6, lane = tid & 63;
    int q = lane >> 4, c16 = lane & 15;

    for (int i = tid; i < T_TREES * N_NODES; i += THREADS) { lv_s[i] = lv0[i]; bias_s[i] = bias_p[i]; }

    float* spb = sp_all[wave];
    int rowBase = blockIdx.x * M_TILE + wave * 16;   // this wave's 16 rows

    // A fragments: bf16(x) for 16 rows -> 4 x bf16x8. A-layout m=lane&15, k=q*8+j.
    bf16x8 afrag[4];
    {
        const float* xr = x + (size_t)(rowBase + c16) * F_DIM;
        #pragma unroll
        for (int ks = 0; ks < 4; ++ks) {
            const float4* p = (const float4*)(xr + ks * 32 + q * 8);
            float4 f0 = p[0], f1 = p[1];
            bf16x8 v;
            v[0]=f2bf(f0.x); v[1]=f2bf(f0.y); v[2]=f2bf(f0.z); v[3]=f2bf(f0.w);
            v[4]=f2bf(f1.x); v[5]=f2bf(f1.y); v[6]=f2bf(f1.z); v[7]=f2bf(f1.w);
            afrag[ks] = v;
        }
    }

    // staging geometry: thread tid owns 16 B chunk tid of the 8 KB tree image
    // (row n = tid>>4). Swizzle: phys = lin ^ ((row&7)<<4), same fn on read.
    const unsigned soff = (unsigned)(tid * 16) ^ ((unsigned)((tid >> 4) & 7u) << 4);

    // prologue: stage tree 0 into buffer 0
    {
        bf16x8 s0 = ((const bf16x8*)w_all)[tid];
        *(bf16x8*)((char*)bstage[0] + soff) = s0;
    }

    int s = lane & 15, h = lane >> 4;   // leaf job: row s, quarter-subtree h
    int s_node = 3 + h;                 // quarter root (level-2 node)
    float acc0 = 0.f;
    __syncthreads();                    // lv/bias + tree-0 stage ready

    #pragma unroll
    for (int t = 0; t < T_TREES; ++t) {
        const int cur = t & 1, nxt = cur ^ 1;   // static under full unroll
        // 1) issue next tree's global load EARLY (hides under this tree's compute)
        bf16x8 pf;
        if (t + 1 < T_TREES)
            pf = ((const bf16x8*)(w_all + (t + 1) * (N_NODES * F_DIM)))[tid];

        // 2) B fragments from LDS (swizzled read, bytes identical to r8-verified)
        bf16x8 bfrag[2][4];
        const char* bb = (const char*)bstage[cur];
        #pragma unroll
        for (int ni = 0; ni < 2; ++ni) {
            unsigned row = (unsigned)(ni * 16 + c16);
            unsigned swz = (row & 7u) << 4;
            #pragma unroll
            for (int ks = 0; ks < 4; ++ks) {
                unsigned lin = row * 256u + (unsigned)(ks * 64 + q * 16);
                bfrag[ni][ks] = *(const bf16x8*)(bb + (lin ^ swz));
            }
        }

        floatx4 acc[2];
        acc[0] = (floatx4){0.f,0.f,0.f,0.f};
        acc[1] = (floatx4){0.f,0.f,0.f,0.f};
        #pragma unroll
        for (int ks = 0; ks < 4; ++ks)
            #pragma unroll
            for (int ni = 0; ni < 2; ++ni)
                acc[ni] = __builtin_amdgcn_mfma_f32_16x16x32_bf16(
                    afrag[ks], bfrag[ni][ks], acc[ni], 0, 0, 0);

        // 3) epilogue: u = fma(acc, -log2e, bias*(-log2e)); sigma = rcp(1+2^u);
        // transposed wave-private store (scalar b32: stride 17 is not 16B-aligned)
        #pragma unroll
        for (int ni = 0; ni < 2; ++ni) {
            int col = ni * 16 + c16;
            float bv = bias_s[t * N_NODES + col];
            #pragma unroll
            for (int j = 0; j < 4; ++j)
                spb[col * S_SP2 + q * 4 + j] =
                    sig_from_scaled(fmaf(acc[ni][j], -NLOG2E, bv));
        }
        // 4) leaf phase: wave-private LDS, in-order per wave -> no barrier needed.
        float g0 = spb[s];
        int n1 = 1 + (h >> 1);
        float g1 = spb[n1 * S_SP2 + s];
        float g2 = spb[s_node * S_SP2 + s];
        int n3a = 2 * s_node + 1, n3b = 2 * s_node + 2;
        float g3a = spb[n3a * S_SP2 + s], g3b = spb[n3b * S_SP2 + s];
        int n4 = 4 * s_node + 3;
        float g4a = spb[n4 * S_SP2 + s],       g4b = spb[(n4+1) * S_SP2 + s];
        float g4c = spb[(n4+2) * S_SP2 + s],   g4d = spb[(n4+3) * S_SP2 + s];

        const float* lvt = &lv_s[t * N_NODES + h * 8];
        {
            float f0 = (h & 2) ? g0 : 1.f - g0;
            float f1 = (h & 1) ? g1 : 1.f - g1;
            float pre = f0 * f1;
            float p1 = pre * g2, p0 = pre - p1;
            float q1 = p0 * g3a, q0 = p0 - q1;
            float q3 = p1 * g3b, q2 = p1 - q3;
            float r1 = q0 * g4a, r0 = q0 - r1;
            float r3 = q1 * g4b, r2 = q1 - r3;
            float r5 = q2 * g4c, r4 = q2 - r5;
            float r7 = q3 * g4d, r6 = q3 - r7;
            acc0 += r0*lvt[0] + r1*lvt[1] + r2*lvt[2] + r3*lvt[3]
                  + r4*lvt[4] + r5*lvt[5] + r6*lvt[6] + r7*lvt[7];
        }

        // 5) write the prefetched tree into the other buffer, then one barrier.
        if (t + 1 < T_TREES)
            *(bf16x8*)((char*)bstage[nxt] + soff) = pf;
        __syncthreads();
    }

    // cross-quarter reduce inside the wave; out1 = 1 - out0 (prob mass sums to 1)
    acc0 += __shfl_xor(acc0, 16, 64);
    acc0 += __shfl_xor(acc0, 32, 64);
    if (h == 0) {
        float2 o; o.x = acc0; o.y = 1.f - acc0;
        *(float2*)(out + (size_t)(rowBase + s) * 2) = o;
    }
}

extern "C" void kernel_launch(void* const* d_in, const int* in_sizes, int n_in,
                              void* d_out, int out_size, void* d_ws, size_t ws_size,
                              hipStream_t stream) {
    const float* x  = (const float*)d_in[0];
    const float* sw = (const float*)d_in[1];
    const float* sb = (const float*)d_in[2];
    const float* ll = (const float*)d_in[3];
    const float* tw = (const float*)d_in[4];
    const float* fm = (const float*)d_in[5];
    float* out = (float*)d_out;

    short* w_all  = (short*)d_ws;                         // 20*32*128*2 = 163840 B
    float* bias_p = (float*)((char*)d_ws + 163840);       // 2560 B
    float* lv0    = (float*)((char*)d_ws + 166400);       // 2560 B

    dim3 pgrid(T_TREES, 8);
    nrf_prep<<<pgrid, 256, 0, stream>>>(sw, sb, ll, tw, fm, w_all, bias_p, lv0);

    int B = in_sizes[0] / F_DIM;                          // 131072
    nrf_main<<<B / M_TILE, THREADS, 0, stream>>>(x, w_all, bias_p, lv0, out);
}

// Round 12
// 144.786 us; speedup vs baseline: 1.7692x; 1.7692x over previous
//
#include <hip/hip_runtime.h>

typedef __attribute__((ext_vector_type(8))) short bf16x8;
typedef __attribute__((ext_vector_type(4))) float floatx4;

#define T_TREES 20
#define N_NODES 32      // padded (31 real internal nodes)
#define F_DIM 128
#define M_TILE 128      // 8 waves x 16 rows each, wave-private leaf phase
#define THREADS 512
#define S_SP2 17        // sp stride (dwords): 16 rows + 1 pad, odd -> conflict-free

#define NLOG2E 1.4426950408889634f   // sigmoid scale, applied in EPILOGUE (fma)

__device__ __forceinline__ short f2bf(float f) {
    unsigned u = __float_as_uint(f);
    u += 0x7fffu + ((u >> 16) & 1u);   // RNE — matches numpy/ml_dtypes bf16 cast
    return (short)(u >> 16);
}
__device__ __forceinline__ float bf2f(short h) {
    return __uint_as_float(((unsigned)(unsigned short)h) << 16);
}

// sigma(z) with u = -z*log2(e) already: 1/(1+2^u). 2 VALU + 2 trans ops.
__device__ __forceinline__ float sig_from_scaled(float u) {
    return __builtin_amdgcn_rcpf(1.f + __builtin_amdgcn_exp2f(u));
}

// ---------------- prep: RAW bf16 masked weights (unscaled -> exact bf16 grid).
// Parallel: grid (20 trees, 8 node-slices); tw staged via LDS; softmax order identical.
__global__ void nrf_prep(const float* __restrict__ sw, const float* __restrict__ sb,
                         const float* __restrict__ ll, const float* __restrict__ tw,
                         const float* __restrict__ fm,
                         short* __restrict__ w_all, float* __restrict__ bias_p,
                         float* __restrict__ lv0) {
    int t = blockIdx.x, slice = blockIdx.y, tid = threadIdx.x;

    const float* fmt = fm + t * F_DIM;
    const float* swt = sw + t * 31 * F_DIM;
    int idx = slice * 512 + tid;          // 4 nodes x 128 feats per slice
    #pragma unroll
    for (int r = 0; r < 2; ++r, idx += 256) {
        int n = idx >> 7, f = idx & 127;
        // mask is 0/1: bf16(sw*fm) == bf16(sw)*fm exactly. Store UNSCALED bf16.
        short wb = (n < 31 && fmt[f] != 0.f) ? f2bf(swt[n * F_DIM + f]) : (short)0;
        w_all[t * (N_NODES * F_DIM) + idx] = wb;
    }

    if (slice == 0) {
        __shared__ float tws[T_TREES];
        if (tid < T_TREES) tws[tid] = tw[tid];
        __syncthreads();
        if (tid < N_NODES) {
            // same reduction ORDER as the verified kernel -> bit-identical wt
            float m = -1e30f;
            for (int i = 0; i < T_TREES; ++i) m = fmaxf(m, bf2f(f2bf(tws[i])));
            float s = 0.f;
            for (int i = 0; i < T_TREES; ++i) s += __expf(bf2f(f2bf(tws[i])) - m);
            float wt = __expf(bf2f(f2bf(tws[t])) - m) / s;

            float bv = (tid < 31) ? bf2f(f2bf(sb[t * 31 + tid])) : 0.f;
            bias_p[t * N_NODES + tid] = bv * (-NLOG2E);
            float a  = bf2f(f2bf(ll[(t * 32 + tid) * 2 + 0]));
            float bb = bf2f(f2bf(ll[(t * 32 + tid) * 2 + 1]));
            float mx = fmaxf(a, bb);
            float e0 = __expf(a - mx), e1 = __expf(bb - mx);
            lv0[t * N_NODES + tid] = wt * e0 / (e0 + e1);
        }
    }
}

// ---------------- main: 8 waves x 16 rows. r11 structure, but launch_bounds(512,6):
// 85-reg/wave budget (r11's (512,8)=64 forced catastrophic spills: VGPR=32,
// 550 MB scratch traffic). 6 waves/SIMD = 24 waves/CU = 1.5x r8's TLP.
// Per-row op sequence, MFMA chain order, sigmoid, leaf chain: bit-identical to r8.
__global__ __launch_bounds__(THREADS, 6) void nrf_main(const float* __restrict__ x,
        const short* __restrict__ w_all, const float* __restrict__ bias_p,
        const float* __restrict__ lv0, float* __restrict__ out) {
    __shared__ short bstage[2][N_NODES * F_DIM];   // 2 x 8 KB, XOR-swizzled rows
    __shared__ float sp_all[8][N_NODES * S_SP2];   // one 16-row patch per wave
    __shared__ float lv_s[T_TREES * N_NODES];
    __shared__ float bias_s[T_TREES * N_NODES];

    int tid = threadIdx.x;
    int wave = tid >> 6, lane = tid & 63;
    int q = lane >> 4, c16 = lane & 15;

    for (int i = tid; i < T_TREES * N_NODES; i += THREADS) { lv_s[i] = lv0[i]; bias_s[i] = bias_p[i]; }

    float* spb = sp_all[wave];
    int rowBase = blockIdx.x * M_TILE + wave * 16;   // this wave's 16 rows

    // A fragments: bf16(x) for 16 rows -> 4 x bf16x8. A-layout m=lane&15, k=q*8+j.
    bf16x8 afrag[4];
    {
        const float* xr = x + (size_t)(rowBase + c16) * F_DIM;
        #pragma unroll
        for (int ks = 0; ks < 4; ++ks) {
            const float4* p = (const float4*)(xr + ks * 32 + q * 8);
            float4 f0 = p[0], f1 = p[1];
            bf16x8 v;
            v[0]=f2bf(f0.x); v[1]=f2bf(f0.y); v[2]=f2bf(f0.z); v[3]=f2bf(f0.w);
            v[4]=f2bf(f1.x); v[5]=f2bf(f1.y); v[6]=f2bf(f1.z); v[7]=f2bf(f1.w);
            afrag[ks] = v;
        }
    }

    // staging geometry: thread tid owns 16 B chunk tid of the 8 KB tree image
    // (row n = tid>>4). Swizzle: phys = lin ^ ((row&7)<<4), same fn on read.
    const unsigned soff = (unsigned)(tid * 16) ^ ((unsigned)((tid >> 4) & 7u) << 4);

    // prologue: stage tree 0 into buffer 0
    {
        bf16x8 s0 = ((const bf16x8*)w_all)[tid];
        *(bf16x8*)((char*)bstage[0] + soff) = s0;
    }

    int s = lane & 15, h = lane >> 4;   // leaf job: row s, quarter-subtree h
    int s_node = 3 + h;                 // quarter root (level-2 node)
    float acc0 = 0.f;
    __syncthreads();                    // lv/bias + tree-0 stage ready

    #pragma unroll
    for (int t = 0; t < T_TREES; ++t) {
        const int cur = t & 1, nxt = cur ^ 1;   // static under full unroll
        // 1) issue next tree's global load EARLY (hides under this tree's compute)
        bf16x8 pf;
        if (t + 1 < T_TREES)
            pf = ((const bf16x8*)(w_all + (t + 1) * (N_NODES * F_DIM)))[tid];

        // 2) B fragments from LDS (swizzled read, bytes identical to r8-verified)
        bf16x8 bfrag[2][4];
        const char* bb = (const char*)bstage[cur];
        #pragma unroll
        for (int ni = 0; ni < 2; ++ni) {
            unsigned row = (unsigned)(ni * 16 + c16);
            unsigned swz = (row & 7u) << 4;
            #pragma unroll
            for (int ks = 0; ks < 4; ++ks) {
                unsigned lin = row * 256u + (unsigned)(ks * 64 + q * 16);
                bfrag[ni][ks] = *(const bf16x8*)(bb + (lin ^ swz));
            }
        }

        floatx4 acc[2];
        acc[0] = (floatx4){0.f,0.f,0.f,0.f};
        acc[1] = (floatx4){0.f,0.f,0.f,0.f};
        #pragma unroll
        for (int ks = 0; ks < 4; ++ks)
            #pragma unroll
            for (int ni = 0; ni < 2; ++ni)
                acc[ni] = __builtin_amdgcn_mfma_f32_16x16x32_bf16(
                    afrag[ks], bfrag[ni][ks], acc[ni], 0, 0, 0);

        // 3) epilogue: u = fma(acc, -log2e, bias*(-log2e)); sigma = rcp(1+2^u);
        // transposed wave-private store (scalar b32: stride 17 is not 16B-aligned)
        #pragma unroll
        for (int ni = 0; ni < 2; ++ni) {
            int col = ni * 16 + c16;
            float bv = bias_s[t * N_NODES + col];
            #pragma unroll
            for (int j = 0; j < 4; ++j)
                spb[col * S_SP2 + q * 4 + j] =
                    sig_from_scaled(fmaf(acc[ni][j], -NLOG2E, bv));
        }
        // 4) leaf phase: wave-private LDS, in-order per wave -> no barrier needed.
        float g0 = spb[s];
        int n1 = 1 + (h >> 1);
        float g1 = spb[n1 * S_SP2 + s];
        float g2 = spb[s_node * S_SP2 + s];
        int n3a = 2 * s_node + 1, n3b = 2 * s_node + 2;
        float g3a = spb[n3a * S_SP2 + s], g3b = spb[n3b * S_SP2 + s];
        int n4 = 4 * s_node + 3;
        float g4a = spb[n4 * S_SP2 + s],       g4b = spb[(n4+1) * S_SP2 + s];
        float g4c = spb[(n4+2) * S_SP2 + s],   g4d = spb[(n4+3) * S_SP2 + s];

        const float* lvt = &lv_s[t * N_NODES + h * 8];
        {
            float f0 = (h & 2) ? g0 : 1.f - g0;
            float f1 = (h & 1) ? g1 : 1.f - g1;
            float pre = f0 * f1;
            float p1 = pre * g2, p0 = pre - p1;
            float q1 = p0 * g3a, q0 = p0 - q1;
            float q3 = p1 * g3b, q2 = p1 - q3;
            float r1 = q0 * g4a, r0 = q0 - r1;
            float r3 = q1 * g4b, r2 = q1 - r3;
            float r5 = q2 * g4c, r4 = q2 - r5;
            float r7 = q3 * g4d, r6 = q3 - r7;
            acc0 += r0*lvt[0] + r1*lvt[1] + r2*lvt[2] + r3*lvt[3]
                  + r4*lvt[4] + r5*lvt[5] + r6*lvt[6] + r7*lvt[7];
        }

        // 5) write the prefetched tree into the other buffer, then one barrier.
        if (t + 1 < T_TREES)
            *(bf16x8*)((char*)bstage[nxt] + soff) = pf;
        __syncthreads();
    }

    // cross-quarter reduce inside the wave; out1 = 1 - out0 (prob mass sums to 1)
    acc0 += __shfl_xor(acc0, 16, 64);
    acc0 += __shfl_xor(acc0, 32, 64);
    if (h == 0) {
        float2 o; o.x = acc0; o.y = 1.f - acc0;
        *(float2*)(out + (size_t)(rowBase + s) * 2) = o;
    }
}

extern "C" void kernel_launch(void* const* d_in, const int* in_sizes, int n_in,
                              void* d_out, int out_size, void* d_ws, size_t ws_size,
                              hipStream_t stream) {
    const float* x  = (const float*)d_in[0];
    const float* sw = (const float*)d_in[1];
    const float* sb = (const float*)d_in[2];
    const float* ll = (const float*)d_in[3];
    const float* tw = (const float*)d_in[4];
    const float* fm = (const float*)d_in[5];
    float* out = (float*)d_out;

    short* w_all  = (short*)d_ws;                         // 20*32*128*2 = 163840 B
    float* bias_p = (float*)((char*)d_ws + 163840);       // 2560 B
    float* lv0    = (float*)((char*)d_ws + 166400);       // 2560 B

    dim3 pgrid(T_TREES, 8);
    nrf_prep<<<pgrid, 256, 0, stream>>>(sw, sb, ll, tw, fm, w_all, bias_p, lv0);

    int B = in_sizes[0] / F_DIM;                          // 131072
    nrf_main<<<B / M_TILE, THREADS, 0, stream>>>(x, w_all, bias_p, lv0, out);
}